// Round 1
// baseline (546.532 us; speedup 1.0000x reference)
//
#include <hip/hip_runtime.h>
#include <stdint.h>

// Problem constants: B=8, C(=N_LOCAL=N_GLOBAL=N_PLANE)=512, L(=LQ=LK)=8192, H=8, d=64.

typedef __attribute__((ext_vector_type(8))) short bf16x8;
typedef __attribute__((ext_vector_type(4))) float f32x4;

__device__ __forceinline__ short f2bf(float f) {
  union { float f; uint32_t u; } v; v.f = f;
  uint32_t r = v.u + 0x7FFFu + ((v.u >> 16) & 1u);  // RNE
  return (short)(r >> 16);
}

__device__ __forceinline__ void async_ld16(const void* g, void* l) {
  __builtin_amdgcn_global_load_lds(
      (const __attribute__((address_space(1))) void*)g,
      (__attribute__((address_space(3))) void*)l, 16, 0, 0);
}

// ---------------------------------------------------------------------------
// Weights prep: straight-cast Wk,Wv,Wo to bf16; transpose-cast Wq -> Wqt[c][p].
__launch_bounds__(256)
__global__ void prep_weights(const float* __restrict__ Wq, const float* __restrict__ Wk,
                             const float* __restrict__ Wv, const float* __restrict__ Wo,
                             short* __restrict__ Wqt, short* __restrict__ Wkb,
                             short* __restrict__ Wvb, short* __restrict__ Wob) {
  int i = blockIdx.x * 256 + threadIdx.x;  // 0..262143
  Wkb[i] = f2bf(Wk[i]);
  Wvb[i] = f2bf(Wv[i]);
  Wob[i] = f2bf(Wo[i]);
  int c = i >> 9, p = i & 511;
  Wqt[i] = f2bf(Wq[p * 512 + c]);  // Wqt[c*512+p] = Wq[p][c]
}

// ---------------------------------------------------------------------------
// Transpose+cast X[b][c][l] (fp32) -> Xt[b][l][c] (bf16).  64x64 LDS tiles.
__launch_bounds__(256)
__global__ void transpose_cast(const float* __restrict__ X, short* __restrict__ Xt) {
  __shared__ float tile[64][65];
  const int b = blockIdx.z;
  const int l0 = blockIdx.x * 64, c0 = blockIdx.y * 64;
  const int tx = threadIdx.x & 63, ty = threadIdx.x >> 6;
  const float* Xb = X + (size_t)b * 512 * 8192;
  short* Xtb = Xt + (size_t)b * 512 * 8192;
#pragma unroll
  for (int i = 0; i < 16; i++) {
    int c = ty * 16 + i;
    tile[c][tx] = Xb[(size_t)(c0 + c) * 8192 + l0 + tx];  // coalesced along l
  }
  __syncthreads();
#pragma unroll
  for (int i = 0; i < 16; i++) {
    int l = ty * 16 + i;
    Xtb[(size_t)(l0 + l) * 512 + c0 + tx] = f2bf(tile[tx][l]);  // coalesced along c
  }
}

// ---------------------------------------------------------------------------
// Generic bf16 GEMM, m97 structure: C[b][m][n] = sum_k A[m][k] * B[b][n][k]
// A row-major M x K (optionally batched), B row-major N x K ("B^T layout").
// 128x128 tile, BK=32, 4 waves in 2x2, 16x16x32 MFMA, global_load_lds width 16.
template <bool OUT_BF16, bool A_BATCH>
__launch_bounds__(256)
__global__ void gemm_bt(const short* __restrict__ A, const short* __restrict__ B,
                        void* __restrict__ C, int M, int N, int K) {
  __shared__ __align__(16) short As[128 * 32];
  __shared__ __align__(16) short Bs[128 * 32];
  const int tid = threadIdx.x;
  const int lane = tid & 63;
  const int w = tid >> 6;
  const int wy = w >> 1, wx = w & 1;
  const int m0 = blockIdx.y * 128, n0 = blockIdx.x * 128;
  const size_t b = blockIdx.z;
  const short* Ab = A + (A_BATCH ? b * (size_t)M * K : (size_t)0);
  const short* Bb = B + b * (size_t)N * K;
  const int fr = lane & 15, fkg = lane >> 4;

  f32x4 acc[4][4] = {};

  for (int kk = 0; kk < K; kk += 32) {
    __syncthreads();  // protect LDS from previous iteration's readers
#pragma unroll
    for (int j = 0; j < 2; j++) {
      int ci = j * 256 + w * 64 + lane;        // chunk id 0..511 (16B chunks)
      int row = ci >> 2;                       // tile row 0..127
      int co = (ci & 3) * 8;                   // element offset in row
      async_ld16(Ab + (size_t)(m0 + row) * K + kk + co, &As[(j * 256 + w * 64) * 8]);
      async_ld16(Bb + (size_t)(n0 + row) * K + kk + co, &Bs[(j * 256 + w * 64) * 8]);
    }
    __syncthreads();  // drains vmcnt (global_load_lds) per barrier semantics

    bf16x8 af[4], bf[4];
#pragma unroll
    for (int t = 0; t < 4; t++) {
      af[t] = *(const bf16x8*)&As[(wy * 64 + t * 16 + fr) * 32 + fkg * 8];
      bf[t] = *(const bf16x8*)&Bs[(wx * 64 + t * 16 + fr) * 32 + fkg * 8];
    }
#pragma unroll
    for (int mt = 0; mt < 4; mt++)
#pragma unroll
      for (int nt = 0; nt < 4; nt++)
        acc[mt][nt] =
            __builtin_amdgcn_mfma_f32_16x16x32_bf16(af[mt], bf[nt], acc[mt][nt], 0, 0, 0);
  }

  // Epilogue. C/D layout: col = lane&15, row = (lane>>4)*4 + reg.
  const size_t cbase = b * (size_t)M * N;
#pragma unroll
  for (int mt = 0; mt < 4; mt++) {
#pragma unroll
    for (int nt = 0; nt < 4; nt++) {
      int n = n0 + wx * 64 + nt * 16 + fr;
#pragma unroll
      for (int r = 0; r < 4; r++) {
        int m = m0 + wy * 64 + mt * 16 + fkg * 4 + r;
        float v = acc[mt][nt][r];
        if (OUT_BF16)
          ((short*)C)[cbase + (size_t)m * N + n] = f2bf(v);
        else
          ((float*)C)[cbase + (size_t)m * N + n] = v;
      }
    }
  }
}

// ---------------------------------------------------------------------------
// kv[b][h][d][e] += sum_l K[b][h*64+d][l] * V[b][h*64+e][l]   (fp32 atomics)
// grid (L/2048, H, B), 4 waves; each wave owns an L-chunk of 512, 64x64 output.
__launch_bounds__(256)
__global__ void kv_accum(const short* __restrict__ Kb, const short* __restrict__ Vb,
                         float* __restrict__ kv) {
  const int lane = threadIdx.x & 63, w = threadIdx.x >> 6;
  const int b = blockIdx.z, h = blockIdx.y;
  const int l0 = blockIdx.x * 2048 + w * 512;
  const short* Kh = Kb + ((size_t)b * 512 + h * 64) * 8192 + l0;
  const short* Vh = Vb + ((size_t)b * 512 + h * 64) * 8192 + l0;
  const int fr = lane & 15, fkg = lane >> 4;
  f32x4 acc[4][4] = {};
  for (int kk = 0; kk < 512; kk += 32) {
    bf16x8 af[4], bf[4];
#pragma unroll
    for (int t = 0; t < 4; t++) {
      af[t] = *(const bf16x8*)&Kh[(size_t)(t * 16 + fr) * 8192 + kk + fkg * 8];
      bf[t] = *(const bf16x8*)&Vh[(size_t)(t * 16 + fr) * 8192 + kk + fkg * 8];
    }
#pragma unroll
    for (int mt = 0; mt < 4; mt++)
#pragma unroll
      for (int nt = 0; nt < 4; nt++)
        acc[mt][nt] =
            __builtin_amdgcn_mfma_f32_16x16x32_bf16(af[mt], bf[nt], acc[mt][nt], 0, 0, 0);
  }
  float* kvb = kv + ((size_t)b * 8 + h) * 4096;
#pragma unroll
  for (int mt = 0; mt < 4; mt++)
#pragma unroll
    for (int nt = 0; nt < 4; nt++)
#pragma unroll
      for (int r = 0; r < 4; r++) {
        int d = mt * 16 + fkg * 4 + r, e = nt * 16 + fr;
        atomicAdd(&kvb[d * 64 + e], acc[mt][nt][r]);
      }
}

// ---------------------------------------------------------------------------
// U[p=h*64+e][c] = sum_d kv[b][h][d][e]/64 * Wq[h*64+d][c], stored TRANSPOSED:
// Ut[b][c][p] (bf16) so the next GEMM reads it k-contiguously. grid (H, B).
__launch_bounds__(256)
__global__ void u_compute(const float* __restrict__ kv, const short* __restrict__ Wqt,
                          short* __restrict__ Ut) {
  const int lane = threadIdx.x & 63, w = threadIdx.x >> 6;
  const int h = blockIdx.x, b = blockIdx.y;
  const float* kvb = kv + ((size_t)b * 8 + h) * 4096;
  const int fr = lane & 15, fkg = lane >> 4;
  f32x4 acc[4][8] = {};
#pragma unroll
  for (int ks = 0; ks < 2; ks++) {
    bf16x8 af[4];
#pragma unroll
    for (int mt = 0; mt < 4; mt++) {
      union { short s[8]; bf16x8 v; } u;
#pragma unroll
      for (int j = 0; j < 8; j++) {
        int d = ks * 32 + fkg * 8 + j;
        int e = mt * 16 + fr;
        u.s[j] = f2bf(kvb[d * 64 + e] * 0.015625f);  // A[e][d] = kv[d][e]/64
      }
      af[mt] = u.v;
    }
#pragma unroll
    for (int nt = 0; nt < 8; nt++) {
      int c = w * 128 + nt * 16 + fr;
      bf16x8 bfr = *(const bf16x8*)&Wqt[(size_t)c * 512 + h * 64 + ks * 32 + fkg * 8];
#pragma unroll
      for (int mt = 0; mt < 4; mt++)
        acc[mt][nt] =
            __builtin_amdgcn_mfma_f32_16x16x32_bf16(af[mt], bfr, acc[mt][nt], 0, 0, 0);
    }
  }
  short* Utb = Ut + (size_t)b * 262144;
#pragma unroll
  for (int mt = 0; mt < 4; mt++)
#pragma unroll
    for (int nt = 0; nt < 8; nt++) {
      int c = w * 128 + nt * 16 + fr;
#pragma unroll
      for (int r = 0; r < 4; r++) {
        int e = mt * 16 + fkg * 4 + r;
        Utb[(size_t)c * 512 + h * 64 + e] = f2bf(acc[mt][nt][r]);
      }
    }
}

// ---------------------------------------------------------------------------
extern "C" void kernel_launch(void* const* d_in, const int* in_sizes, int n_in,
                              void* d_out, int out_size, void* d_ws, size_t ws_size,
                              hipStream_t stream) {
  const float* x_local  = (const float*)d_in[0];
  const float* x_global = (const float*)d_in[1];
  const float* Wq = (const float*)d_in[2];
  const float* Wk = (const float*)d_in[3];
  const float* Wv = (const float*)d_in[4];
  const float* Wo = (const float*)d_in[5];

  // Workspace layout (~78.6 MB). Xt region is reused: Xg^T first, then Xl^T.
  char* ws = (char*)d_ws;
  short* Xt  = (short*)(ws + 0);          // 67108864 B : X^T bf16 [b][l][c]
  float* kv  = (float*)(ws + 67108864);   //  1048576 B : kv fp32 [b][h][d][e]
  short* Ut  = (short*)(ws + 68157440);   //  4194304 B : U^T bf16 [b][c][p]
  short* Mb  = (short*)(ws + 72351744);   //  4194304 B : M bf16 [b][o][c]
  short* Wkb = (short*)(ws + 76546048);
  short* Wvb = (short*)(ws + 77070336);
  short* Wob = (short*)(ws + 77594624);
  short* Wqt = (short*)(ws + 78118912);   // end 78643200

  // K,V (bf16, 64 MB each) live in d_out until the final GEMM overwrites it.
  short* Kb = (short*)d_out;
  short* Vb = (short*)((char*)d_out + 67108864);

  prep_weights<<<1024, 256, 0, stream>>>(Wq, Wk, Wv, Wo, Wqt, Wkb, Wvb, Wob);
  hipMemsetAsync(kv, 0, 1048576, stream);

  // Xg^T, then K = Wk@Xg, V = Wv@Xg (bf16, [b][p][l])
  transpose_cast<<<dim3(128, 8, 8), 256, 0, stream>>>(x_global, Xt);
  gemm_bt<true, false><<<dim3(64, 4, 8), 256, 0, stream>>>(Wkb, Xt, Kb, 512, 8192, 512);
  gemm_bt<true, false><<<dim3(64, 4, 8), 256, 0, stream>>>(Wvb, Xt, Vb, 512, 8192, 512);

  // kv Gram matrices, then collapse to M[b] = Wo @ (BD[b]/64) @ Wq
  kv_accum<<<dim3(4, 8, 8), 256, 0, stream>>>(Kb, Vb, kv);
  u_compute<<<dim3(8, 8), 256, 0, stream>>>(kv, Wqt, Ut);
  gemm_bt<true, false><<<dim3(4, 4, 8), 256, 0, stream>>>(Wob, Ut, Mb, 512, 512, 512);

  // Xl^T (reuses Xt region; Xg^T is dead), then Y[b] = M[b] @ Xl[b] -> d_out fp32
  transpose_cast<<<dim3(128, 8, 8), 256, 0, stream>>>(x_local, Xt);
  gemm_bt<false, true><<<dim3(64, 4, 8), 256, 0, stream>>>(Mb, Xt, d_out, 512, 8192, 512);
}

// Round 3
// 516.662 us; speedup vs baseline: 1.0578x; 1.0578x over previous
//
#include <hip/hip_runtime.h>
#include <stdint.h>

// B=8, C(=N_LOCAL=N_GLOBAL=N_PLANE)=512, L(=LQ=LK)=8192, H=8, d=64.
// Y[b] = Wo · blockdiag_h(kv_h^T/64) · Wq · Xl[b],  kv_h = Wk_h · G[b] · Wv_h^T,
// G[b] = Xg[b] Xg[b]^T  (512x512 Gram; K/V never materialized).

typedef __attribute__((ext_vector_type(8))) short bf16x8;
typedef __attribute__((ext_vector_type(4))) float f32x4;

__device__ __forceinline__ short f2bf(float f) {
  union { float f; uint32_t u; } v; v.f = f;
  uint32_t r = v.u + 0x7FFFu + ((v.u >> 16) & 1u);  // RNE
  return (short)(r >> 16);
}

__device__ __forceinline__ void async_ld16(const void* g, void* l) {
  __builtin_amdgcn_global_load_lds(
      (const __attribute__((address_space(1))) void*)g,
      (__attribute__((address_space(3))) void*)l, 16, 0, 0);
}

// ---------------------------------------------------------------------------
// Weights prep: straight-cast Wk,Wv,Wo to bf16; transpose-cast Wq -> Wqt[c][p].
__launch_bounds__(256)
__global__ void prep_weights(const float* __restrict__ Wq, const float* __restrict__ Wk,
                             const float* __restrict__ Wv, const float* __restrict__ Wo,
                             short* __restrict__ Wqt, short* __restrict__ Wkb,
                             short* __restrict__ Wvb, short* __restrict__ Wob) {
  int i = blockIdx.x * 256 + threadIdx.x;  // 0..262143
  Wkb[i] = f2bf(Wk[i]);
  Wvb[i] = f2bf(Wv[i]);
  Wob[i] = f2bf(Wo[i]);
  int c = i >> 9, p = i & 511;
  Wqt[i] = f2bf(Wq[p * 512 + c]);  // Wqt[c*512+p] = Wq[p][c]
}

// ---------------------------------------------------------------------------
// Elementwise cast fp32 -> bf16 (same layout), 8 elems/thread.
// Grid MUST be n_elems/(256*8): for Xg that is 33,554,432/2048 = 16384 blocks.
__launch_bounds__(256)
__global__ void cast_bf16(const float* __restrict__ X, short* __restrict__ Y) {
  size_t i = ((size_t)blockIdx.x * 256 + threadIdx.x) * 8;
  float4 a = *(const float4*)(X + i);
  float4 b = *(const float4*)(X + i + 4);
  union { short s[8]; bf16x8 v; } u;
  u.s[0] = f2bf(a.x); u.s[1] = f2bf(a.y); u.s[2] = f2bf(a.z); u.s[3] = f2bf(a.w);
  u.s[4] = f2bf(b.x); u.s[5] = f2bf(b.y); u.s[6] = f2bf(b.z); u.s[7] = f2bf(b.w);
  *(bf16x8*)(Y + i) = u.v;
}

// ---------------------------------------------------------------------------
// Transpose+cast X[b][c][l] (fp32) -> Xt[b][l][c] (bf16).  64x64 LDS tiles.
__launch_bounds__(256)
__global__ void transpose_cast(const float* __restrict__ X, short* __restrict__ Xt) {
  __shared__ float tile[64][65];
  const int b = blockIdx.z;
  const int l0 = blockIdx.x * 64, c0 = blockIdx.y * 64;
  const int tx = threadIdx.x & 63, ty = threadIdx.x >> 6;
  const float* Xb = X + (size_t)b * 512 * 8192;
  short* Xtb = Xt + (size_t)b * 512 * 8192;
#pragma unroll
  for (int i = 0; i < 16; i++) {
    int c = ty * 16 + i;
    tile[c][tx] = Xb[(size_t)(c0 + c) * 8192 + l0 + tx];  // coalesced along l
  }
  __syncthreads();
#pragma unroll
  for (int i = 0; i < 16; i++) {
    int l = ty * 16 + i;
    Xtb[(size_t)(l0 + l) * 512 + c0 + tx] = f2bf(tile[tx][l]);  // coalesced along c
  }
}

// ---------------------------------------------------------------------------
// Generic bf16 GEMM (m97 structure): C[b][m][n] = sum_k A[m][k] * B[b][n][k].
template <bool OUT_BF16, bool A_BATCH>
__launch_bounds__(256)
__global__ void gemm_bt(const short* __restrict__ A, const short* __restrict__ B,
                        void* __restrict__ C, int M, int N, int K) {
  __shared__ __align__(16) short As[128 * 32];
  __shared__ __align__(16) short Bs[128 * 32];
  const int tid = threadIdx.x;
  const int lane = tid & 63;
  const int w = tid >> 6;
  const int wy = w >> 1, wx = w & 1;
  const int m0 = blockIdx.y * 128, n0 = blockIdx.x * 128;
  const size_t b = blockIdx.z;
  const short* Ab = A + (A_BATCH ? b * (size_t)M * K : (size_t)0);
  const short* Bb = B + b * (size_t)N * K;
  const int fr = lane & 15, fkg = lane >> 4;

  f32x4 acc[4][4] = {};

  for (int kk = 0; kk < K; kk += 32) {
    __syncthreads();
#pragma unroll
    for (int j = 0; j < 2; j++) {
      int ci = j * 256 + w * 64 + lane;
      int row = ci >> 2;
      int co = (ci & 3) * 8;
      async_ld16(Ab + (size_t)(m0 + row) * K + kk + co, &As[(j * 256 + w * 64) * 8]);
      async_ld16(Bb + (size_t)(n0 + row) * K + kk + co, &Bs[(j * 256 + w * 64) * 8]);
    }
    __syncthreads();

    bf16x8 af[4], bf[4];
#pragma unroll
    for (int t = 0; t < 4; t++) {
      af[t] = *(const bf16x8*)&As[(wy * 64 + t * 16 + fr) * 32 + fkg * 8];
      bf[t] = *(const bf16x8*)&Bs[(wx * 64 + t * 16 + fr) * 32 + fkg * 8];
    }
#pragma unroll
    for (int mt = 0; mt < 4; mt++)
#pragma unroll
      for (int nt = 0; nt < 4; nt++)
        acc[mt][nt] =
            __builtin_amdgcn_mfma_f32_16x16x32_bf16(af[mt], bf[nt], acc[mt][nt], 0, 0, 0);
  }

  const size_t cbase = b * (size_t)M * N;
#pragma unroll
  for (int mt = 0; mt < 4; mt++) {
#pragma unroll
    for (int nt = 0; nt < 4; nt++) {
      int n = n0 + wx * 64 + nt * 16 + fr;
#pragma unroll
      for (int r = 0; r < 4; r++) {
        int m = m0 + wy * 64 + mt * 16 + fkg * 4 + r;
        float v = acc[mt][nt][r];
        if (OUT_BF16)
          ((short*)C)[cbase + (size_t)m * N + n] = f2bf(v);
        else
          ((float*)C)[cbase + (size_t)m * N + n] = v;
      }
    }
  }
}

// ---------------------------------------------------------------------------
// Gram partials: Gp[b*8+s][m][n] = sum_{l in chunk s} Xg[b][m][l] Xg[b][n][l].
// Same structure as gemm_bt with A=B=Xgb, K-chunk of 1024, fp32 plain stores.
__launch_bounds__(256)
__global__ void gram_part(const short* __restrict__ X, float* __restrict__ Gp) {
  __shared__ __align__(16) short As[128 * 32];
  __shared__ __align__(16) short Bs[128 * 32];
  const int tid = threadIdx.x;
  const int lane = tid & 63;
  const int w = tid >> 6;
  const int wy = w >> 1, wx = w & 1;
  const int m0 = blockIdx.y * 128, n0 = blockIdx.x * 128;
  const int b = blockIdx.z >> 3, s = blockIdx.z & 7;
  const short* Xb = X + (size_t)b * 512 * 8192;
  const int k0 = s * 1024;
  const int fr = lane & 15, fkg = lane >> 4;

  f32x4 acc[4][4] = {};

  for (int kk = k0; kk < k0 + 1024; kk += 32) {
    __syncthreads();
#pragma unroll
    for (int j = 0; j < 2; j++) {
      int ci = j * 256 + w * 64 + lane;
      int row = ci >> 2;
      int co = (ci & 3) * 8;
      async_ld16(Xb + (size_t)(m0 + row) * 8192 + kk + co, &As[(j * 256 + w * 64) * 8]);
      async_ld16(Xb + (size_t)(n0 + row) * 8192 + kk + co, &Bs[(j * 256 + w * 64) * 8]);
    }
    __syncthreads();

    bf16x8 af[4], bf[4];
#pragma unroll
    for (int t = 0; t < 4; t++) {
      af[t] = *(const bf16x8*)&As[(wy * 64 + t * 16 + fr) * 32 + fkg * 8];
      bf[t] = *(const bf16x8*)&Bs[(wx * 64 + t * 16 + fr) * 32 + fkg * 8];
    }
#pragma unroll
    for (int mt = 0; mt < 4; mt++)
#pragma unroll
      for (int nt = 0; nt < 4; nt++)
        acc[mt][nt] =
            __builtin_amdgcn_mfma_f32_16x16x32_bf16(af[mt], bf[nt], acc[mt][nt], 0, 0, 0);
  }

  float* Gz = Gp + (size_t)blockIdx.z * 262144;
#pragma unroll
  for (int mt = 0; mt < 4; mt++)
#pragma unroll
    for (int nt = 0; nt < 4; nt++) {
      int n = n0 + wx * 64 + nt * 16 + fr;
#pragma unroll
      for (int r = 0; r < 4; r++) {
        int m = m0 + wy * 64 + mt * 16 + fkg * 4 + r;
        Gz[(size_t)m * 512 + n] = acc[mt][nt][r];
      }
    }
}

// ---------------------------------------------------------------------------
// Reduce 8 Gram partials and cast to bf16: Gb[b][r] = bf16(sum_s Gp[b*8+s][r]).
__launch_bounds__(256)
__global__ void g_reduce(const float* __restrict__ Gp, short* __restrict__ Gb) {
  size_t i = ((size_t)blockIdx.x * 256 + threadIdx.x) * 4;  // over 8*512*512
  int b = (int)(i >> 18);
  int r = (int)(i & 262143);
  const float* base = Gp + (size_t)b * 8 * 262144 + r;
  float4 acc = {0.f, 0.f, 0.f, 0.f};
#pragma unroll
  for (int j = 0; j < 8; j++) {
    float4 t = *(const float4*)(base + (size_t)j * 262144);
    acc.x += t.x; acc.y += t.y; acc.z += t.z; acc.w += t.w;
  }
  union { short s[4]; uint64_t u; } o;
  o.s[0] = f2bf(acc.x); o.s[1] = f2bf(acc.y); o.s[2] = f2bf(acc.z); o.s[3] = f2bf(acc.w);
  *(uint64_t*)(Gb + i) = o.u;
}

// ---------------------------------------------------------------------------
// Rt[b][h][e][d] = (1/64) sum_c T'[b][h*64+e][c] * Wk[h*64+d][c]  (= kv[d][e]/64)
// One wave per (b,h): 64x64 out, K=512.
__launch_bounds__(64)
__global__ void r_kernel(const short* __restrict__ Tp, const short* __restrict__ Wkb,
                         short* __restrict__ Rt) {
  const int lane = threadIdx.x;
  const int h = blockIdx.x, b = blockIdx.y;
  const short* Te = Tp + ((size_t)b * 512 + h * 64) * 512;
  const short* Wk = Wkb + (size_t)h * 64 * 512;
  const int fr = lane & 15, fkg = lane >> 4;
  f32x4 acc[4][4] = {};
  for (int kk = 0; kk < 512; kk += 32) {
    bf16x8 af[4], bf[4];
#pragma unroll
    for (int t = 0; t < 4; t++) {
      af[t] = *(const bf16x8*)&Te[(size_t)(t * 16 + fr) * 512 + kk + fkg * 8];
      bf[t] = *(const bf16x8*)&Wk[(size_t)(t * 16 + fr) * 512 + kk + fkg * 8];
    }
#pragma unroll
    for (int mt = 0; mt < 4; mt++)
#pragma unroll
      for (int nt = 0; nt < 4; nt++)
        acc[mt][nt] =
            __builtin_amdgcn_mfma_f32_16x16x32_bf16(af[mt], bf[nt], acc[mt][nt], 0, 0, 0);
  }
  short* Rh = Rt + ((size_t)b * 8 + h) * 4096;  // [e][d]
#pragma unroll
  for (int mt = 0; mt < 4; mt++)
#pragma unroll
    for (int nt = 0; nt < 4; nt++)
#pragma unroll
      for (int r = 0; r < 4; r++) {
        int e = mt * 16 + fkg * 4 + r;   // rows of C = rows of T' slice = e
        int d = nt * 16 + fr;            // cols of C = rows of Wk slice = d
        Rh[e * 64 + d] = f2bf(acc[mt][nt][r] * 0.015625f);
      }
}

// ---------------------------------------------------------------------------
// U[p=h*64+e][c] = sum_d Rt[b][h][e][d] * Wq[h*64+d][c], stored transposed:
// Ut[b][c][p] (bf16). grid (H, B), 4 waves split the 512 c-columns.
__launch_bounds__(256)
__global__ void u_compute(const short* __restrict__ Rt, const short* __restrict__ Wqt,
                          short* __restrict__ Ut) {
  const int lane = threadIdx.x & 63, w = threadIdx.x >> 6;
  const int h = blockIdx.x, b = blockIdx.y;
  const short* Rh = Rt + ((size_t)b * 8 + h) * 4096;
  const int fr = lane & 15, fkg = lane >> 4;
  f32x4 acc[4][8] = {};
#pragma unroll
  for (int ks = 0; ks < 2; ks++) {
    bf16x8 af[4];
#pragma unroll
    for (int mt = 0; mt < 4; mt++)
      af[mt] = *(const bf16x8*)&Rh[(mt * 16 + fr) * 64 + ks * 32 + fkg * 8];
#pragma unroll
    for (int nt = 0; nt < 8; nt++) {
      int c = w * 128 + nt * 16 + fr;
      bf16x8 bfr = *(const bf16x8*)&Wqt[(size_t)c * 512 + h * 64 + ks * 32 + fkg * 8];
#pragma unroll
      for (int mt = 0; mt < 4; mt++)
        acc[mt][nt] =
            __builtin_amdgcn_mfma_f32_16x16x32_bf16(af[mt], bfr, acc[mt][nt], 0, 0, 0);
    }
  }
  short* Utb = Ut + (size_t)b * 262144;
#pragma unroll
  for (int mt = 0; mt < 4; mt++)
#pragma unroll
    for (int nt = 0; nt < 8; nt++) {
      int c = w * 128 + nt * 16 + fr;
#pragma unroll
      for (int r = 0; r < 4; r++) {
        int e = mt * 16 + fkg * 4 + r;
        Utb[(size_t)c * 512 + h * 64 + e] = f2bf(acc[mt][nt][r]);
      }
    }
}

// ---------------------------------------------------------------------------
extern "C" void kernel_launch(void* const* d_in, const int* in_sizes, int n_in,
                              void* d_out, int out_size, void* d_ws, size_t ws_size,
                              hipStream_t stream) {
  const float* x_local  = (const float*)d_in[0];
  const float* x_global = (const float*)d_in[1];
  const float* Wq = (const float*)d_in[2];
  const float* Wk = (const float*)d_in[3];
  const float* Wv = (const float*)d_in[4];
  const float* Wo = (const float*)d_in[5];

  // ws layout (78,118,912 B total)
  char* ws = (char*)d_ws;
  short* Xlt = (short*)(ws + 0);           // 67,108,864 : Xl^T bf16 [b][l][c]
  short* Rt  = (short*)(ws + 67108864);    //    524,288 : kv^T/64 bf16 [b][h][e][d]
  short* Ut  = (short*)(ws + 67633152);    //  4,194,304 : U^T bf16 [b][c][p]
  short* Mb  = (short*)(ws + 71827456);    //  4,194,304 : M bf16 [b][o][c]
  short* Wkb = (short*)(ws + 76021760);
  short* Wvb = (short*)(ws + 76546048);
  short* Wob = (short*)(ws + 77070336);
  short* Wqt = (short*)(ws + 77594624);

  // d_out doubles as scratch until the final GEMM overwrites it (all stream-
  // ordered): phase A: Xgb [0,67M), Gpart [67M,134M). phase B: Gb [0,4M),
  // T' [4M,8M).
  short* Xgb   = (short*)d_out;
  float* Gpart = (float*)((char*)d_out + 67108864);
  short* Gb    = (short*)d_out;
  short* Tp    = (short*)((char*)d_out + 4194304);

  prep_weights<<<1024, 256, 0, stream>>>(Wq, Wk, Wv, Wo, Wqt, Wkb, Wvb, Wob);

  // Xl^T early (independent of the Gram chain).
  transpose_cast<<<dim3(128, 8, 8), 256, 0, stream>>>(x_local, Xlt);

  // Gram chain: cast Xg -> bf16 (native [c][l] layout), split-K Gram, reduce.
  // Xg has 8*512*8192 = 33,554,432 elems; 2048 elems/block -> 16384 blocks.
  cast_bf16<<<16384, 256, 0, stream>>>(x_global, Xgb);
  gram_part<<<dim3(4, 4, 64), 256, 0, stream>>>(Xgb, Gpart);
  g_reduce<<<2048, 256, 0, stream>>>(Gpart, Gb);

  // T'[b] = Wv @ G[b]  (G symmetric), then kv^T/64, then U^T, then M = Wo @ U.
  gemm_bt<true, false><<<dim3(4, 4, 8), 256, 0, stream>>>(Wvb, Gb, Tp, 512, 512, 512);
  r_kernel<<<dim3(8, 8), 64, 0, stream>>>(Tp, Wkb, Rt);
  u_compute<<<dim3(8, 8), 256, 0, stream>>>(Rt, Wqt, Ut);
  gemm_bt<true, false><<<dim3(4, 4, 8), 256, 0, stream>>>(Wob, Ut, Mb, 512, 512, 512);

  // Y[b] = M[b] @ Xl[b] -> d_out fp32 [b][o][l]
  gemm_bt<false, true><<<dim3(64, 4, 8), 256, 0, stream>>>(Mb, Xlt, d_out, 512, 8192, 512);
}